// Round 7
// baseline (225.038 us; speedup 1.0000x reference)
//
#include <hip/hip_runtime.h>
#include <hip/hip_bf16.h>
#include <math.h>

// Problem constants
#define BQ 4
#define NQ 100
#define MQ 50
#define HWSZ 65536
#define NP 112   // padded N rows in partials (7 x 16)
#define MP 64    // padded M (4 x 16)
#define BK 32    // K depth (f32 elems) per pipeline step (one 16x16x32 MFMA K)
#define DCLAMP 13.8155106f   // logit(1-1e-6) = -logit(1e-6)

typedef __attribute__((ext_vector_type(8))) short short8;
typedef __attribute__((ext_vector_type(4))) float f32x4;

// pack two floats -> two bf16 (RTNE) in one u32
__device__ __forceinline__ unsigned pk2(float a, float b) {
    __hip_bfloat162 h = __float22bfloat162_rn(float2{a, b});
    unsigned u; __builtin_memcpy(&u, &h, 4); return u;
}

// build a bf16x8 MFMA fragment from 8 consecutive floats (two float4)
__device__ __forceinline__ short8 mk8(float4 a, float4 b) {
    union { short8 s; unsigned u[4]; } r;
    r.u[0] = pk2(a.x, a.y); r.u[1] = pk2(a.z, a.w);
    r.u[2] = pk2(b.x, b.y); r.u[3] = pk2(b.z, b.w);
    return r.s;
}

// d = log(pm)-log(1-pm) = clamp(x, +-13.8155) EXACTLY (logit o clip o sigmoid).
// pm = sigmoid(clamp(x)); l1m = log(1-pm) = -log(1+e^xc).
__device__ __forceinline__ void xform2(float x, float& d, float& pm, float& l1m) {
    float xc = fminf(fmaxf(x, -DCLAMP), DCLAMP);
    d = xc;
    float e = __expf(xc);                       // in [1e-6, 1e6], no overflow
    float r = __builtin_amdgcn_rcpf(1.0f + e);
    pm = e * r;
    l1m = -__logf(1.0f + e);
}

// transform 8 floats -> d-frag + pm-frag (MFMA operand layout), accumulate row sums
__device__ __forceinline__ void xf8(float4 u, float4 v, short8& fd, short8& fp,
                                    float& rsl, float& rsp) {
    float d0,d1,d2,d3,d4,d5,d6,d7, p0,p1,p2,p3,p4,p5,p6,p7, l;
    xform2(u.x, d0, p0, l); rsl += l;
    xform2(u.y, d1, p1, l); rsl += l;
    xform2(u.z, d2, p2, l); rsl += l;
    xform2(u.w, d3, p3, l); rsl += l;
    xform2(v.x, d4, p4, l); rsl += l;
    xform2(v.y, d5, p5, l); rsl += l;
    xform2(v.z, d6, p6, l); rsl += l;
    xform2(v.w, d7, p7, l); rsl += l;
    rsp += (p0 + p1) + (p2 + p3) + ((p4 + p5) + (p6 + p7));
    union { short8 s; unsigned w[4]; } rd, rp;
    rd.w[0] = pk2(d0, d1); rd.w[1] = pk2(d2, d3); rd.w[2] = pk2(d4, d5); rd.w[3] = pk2(d6, d7);
    rp.w[0] = pk2(p0, p1); rp.w[1] = pk2(p2, p3); rp.w[2] = pk2(p4, p5); rp.w[3] = pk2(p6, p7);
    fd = rd.s; fp = rp.s;
}

__device__ __forceinline__ float sum8(float4 a, float4 b) {
    return (a.x + a.y) + (a.z + a.w) + ((b.x + b.y) + (b.z + b.w));
}

#define MFMA16(A, B, C) __builtin_amdgcn_mfma_f32_16x16x32_bf16(A, B, C, 0, 0, 0)

// Barrier-free main kernel. One WAVE = one (b, chunk, n-tile) job, fully
// independent: loads A directly in MFMA operand layout, transforms in-register
// (each element exactly once), loads B fragments for all 4 m-tiles direct from
// global (binary data; re-reads served by L1/L2/L3 — the 4 waves of a block
// share (b,chunk) so B hits CU-local cache). Zero LDS, zero __syncthreads.
// Depth-2 A prefetch (HBM latency), depth-1 B prefetch (cache latency), all
// in NAMED registers (constant indices only — no scratch demotion).
__global__ __launch_bounds__(256)
void matcher_main(const float* __restrict__ pred_masks,  // [4][100][65536]
                  const float* __restrict__ tgt_masks,   // [4][50][65536]
                  float* __restrict__ part1,             // [4][nch][112][64]
                  float* __restrict__ part2,             // [4][nch][112][64]
                  float* __restrict__ rspart,            // [4][nch][112][2]
                  float* __restrict__ tspart,            // [4][nch][64]
                  int nch, int Kc)
{
    const int wj = blockIdx.x * 4 + (threadIdx.x >> 6);   // wave job id
    const int l  = threadIdx.x & 63;
    const int jb = nch * 7;
    const int b  = wj / jb;
    const int r  = wj % jb;
    const int chunk = r / 7;           // consecutive waves share (b,chunk): B cache reuse
    const int nt    = r % 7;           // n-tile 0..6
    const int m15 = l & 15;
    const int ks8 = (l >> 4) * 8;
    const long kb = (long)chunk * Kc;
    const int nsteps = Kc / BK;        // even (Kc = 65536/nch, nch pow2 <= 128)

    // A pointer: operand layout row = nt*16 + (lane&15) (clamped; rows 100..111
    // produce finite garbage partials the epilogue never reads)
    const int arow = min(nt * 16 + m15, NQ - 1);
    const float* pa = pred_masks + (((long)(b * NQ + arow)) << 16) + kb + ks8;
    // B pointers per m-tile (row-clamped likewise for m >= 50)
    const float* pb0 = tgt_masks + (((long)(b * MQ + min( 0 + m15, MQ - 1))) << 16) + kb + ks8;
    const float* pb1 = tgt_masks + (((long)(b * MQ + min(16 + m15, MQ - 1))) << 16) + kb + ks8;
    const float* pb2 = tgt_masks + (((long)(b * MQ + min(32 + m15, MQ - 1))) << 16) + kb + ks8;
    const float* pb3 = tgt_masks + (((long)(b * MQ + min(48 + m15, MQ - 1))) << 16) + kb + ks8;

    f32x4 acc1[4], acc2[4];
    #pragma unroll
    for (int i = 0; i < 4; i++) { acc1[i] = (f32x4){0.f,0.f,0.f,0.f}; acc2[i] = (f32x4){0.f,0.f,0.f,0.f}; }
    float rsl = 0.f, rsp = 0.f;
    float ts0 = 0.f, ts1 = 0.f, ts2 = 0.f, ts3 = 0.f;
    const bool do_ts = (nt == 0);

    // prologue: B(step0) then A(step0), A(step1)  — FIFO consume order = issue order
    float4 b00 = *(const float4*)(pb0), b01 = *(const float4*)(pb0 + 4);
    float4 b10 = *(const float4*)(pb1), b11 = *(const float4*)(pb1 + 4);
    float4 b20 = *(const float4*)(pb2), b21 = *(const float4*)(pb2 + 4);
    float4 b30 = *(const float4*)(pb3), b31 = *(const float4*)(pb3 + 4);
    float4 a0x = *(const float4*)(pa),      a0y = *(const float4*)(pa + 4);
    float4 a1x = *(const float4*)(pa + BK), a1y = *(const float4*)(pa + BK + 4);
    pa += 2 * BK;

    for (int s = 0; s < nsteps; s += 2) {
        // ================= even step (A parity 0) =================
        {
            // consume B(s): convert to fragments, optional column sums
            const short8 bf0 = mk8(b00, b01), bf1 = mk8(b10, b11);
            const short8 bf2 = mk8(b20, b21), bf3 = mk8(b30, b31);
            if (do_ts) { ts0 += sum8(b00, b01); ts1 += sum8(b10, b11);
                         ts2 += sum8(b20, b21); ts3 += sum8(b30, b31); }
            // issue B(s+1)
            if (s + 1 < nsteps) {
                pb0 += BK; pb1 += BK; pb2 += BK; pb3 += BK;
                b00 = *(const float4*)(pb0); b01 = *(const float4*)(pb0 + 4);
                b10 = *(const float4*)(pb1); b11 = *(const float4*)(pb1 + 4);
                b20 = *(const float4*)(pb2); b21 = *(const float4*)(pb2 + 4);
                b30 = *(const float4*)(pb3); b31 = *(const float4*)(pb3 + 4);
            }
            // consume A(s): transform to d/pm fragments
            short8 fd, fp;
            xf8(a0x, a0y, fd, fp, rsl, rsp);
            // issue A(s+2)
            if (s + 2 < nsteps) {
                a0x = *(const float4*)(pa); a0y = *(const float4*)(pa + 4); pa += BK;
            }
            // MFMA: 4 m-tiles x 2 matrices
            acc1[0] = MFMA16(fd, bf0, acc1[0]); acc2[0] = MFMA16(fp, bf0, acc2[0]);
            acc1[1] = MFMA16(fd, bf1, acc1[1]); acc2[1] = MFMA16(fp, bf1, acc2[1]);
            acc1[2] = MFMA16(fd, bf2, acc1[2]); acc2[2] = MFMA16(fp, bf2, acc2[2]);
            acc1[3] = MFMA16(fd, bf3, acc1[3]); acc2[3] = MFMA16(fp, bf3, acc2[3]);
        }
        // ================= odd step (A parity 1) =================
        {
            const short8 bf0 = mk8(b00, b01), bf1 = mk8(b10, b11);
            const short8 bf2 = mk8(b20, b21), bf3 = mk8(b30, b31);
            if (do_ts) { ts0 += sum8(b00, b01); ts1 += sum8(b10, b11);
                         ts2 += sum8(b20, b21); ts3 += sum8(b30, b31); }
            if (s + 2 < nsteps) {
                pb0 += BK; pb1 += BK; pb2 += BK; pb3 += BK;
                b00 = *(const float4*)(pb0); b01 = *(const float4*)(pb0 + 4);
                b10 = *(const float4*)(pb1); b11 = *(const float4*)(pb1 + 4);
                b20 = *(const float4*)(pb2); b21 = *(const float4*)(pb2 + 4);
                b30 = *(const float4*)(pb3); b31 = *(const float4*)(pb3 + 4);
            }
            short8 fd, fp;
            xf8(a1x, a1y, fd, fp, rsl, rsp);
            if (s + 3 < nsteps) {
                a1x = *(const float4*)(pa); a1y = *(const float4*)(pa + 4); pa += BK;
            }
            acc1[0] = MFMA16(fd, bf0, acc1[0]); acc2[0] = MFMA16(fp, bf0, acc2[0]);
            acc1[1] = MFMA16(fd, bf1, acc1[1]); acc2[1] = MFMA16(fp, bf1, acc2[1]);
            acc1[2] = MFMA16(fd, bf2, acc1[2]); acc2[2] = MFMA16(fp, bf2, acc2[2]);
            acc1[3] = MFMA16(fd, bf3, acc1[3]); acc2[3] = MFMA16(fp, bf3, acc2[3]);
        }
    }

    // ---- store C partials: C/D layout col=lane&15, row=(lane>>4)*4+reg ----
    const long pbase = ((long)(b * nch + chunk)) * NP * MP;
    const int nr0 = (l >> 4) * 4;
    #pragma unroll
    for (int mt = 0; mt < 4; ++mt) {
        #pragma unroll
        for (int rr = 0; rr < 4; ++rr) {
            const int ng = nt * 16 + nr0 + rr;
            part1[pbase + ng * MP + mt * 16 + m15] = acc1[mt][rr];
            part2[pbase + ng * MP + mt * 16 + m15] = acc2[mt][rr];
        }
    }

    // ---- row sums: lanes {m,m+16,m+32,m+48} hold row m's k-slices ----
    rsl += __shfl_xor(rsl, 16); rsl += __shfl_xor(rsl, 32);
    rsp += __shfl_xor(rsp, 16); rsp += __shfl_xor(rsp, 32);
    if (l < 16) {
        const long rb = ((long)(b * nch + chunk) * NP + nt * 16 + l) * 2;
        rspart[rb + 0] = rsl;
        rspart[rb + 1] = rsp;
    }
    // ---- tm column sums (nt==0 waves only) ----
    if (do_ts) {
        ts0 += __shfl_xor(ts0, 16); ts0 += __shfl_xor(ts0, 32);
        ts1 += __shfl_xor(ts1, 16); ts1 += __shfl_xor(ts1, 32);
        ts2 += __shfl_xor(ts2, 16); ts2 += __shfl_xor(ts2, 32);
        ts3 += __shfl_xor(ts3, 16); ts3 += __shfl_xor(ts3, 32);
        if (l < 16) {
            const long tb = (long)(b * nch + chunk) * MP;
            tspart[tb +  0 + l] = ts0;
            tspart[tb + 16 + l] = ts1;
            tspart[tb + 32 + l] = ts2;
            tspart[tb + 48 + l] = ts3;
        }
    }
}

// Epilogue: one block per (b,n), 1024 threads; 16-way chunk-group reduction.
__global__ __launch_bounds__(1024)
void matcher_epilogue(const float* __restrict__ pred_logits, // [4][100][2]
                      const float* __restrict__ pred_style,  // [4][100][4]
                      const int*   __restrict__ styles,      // [4][50]
                      const float* __restrict__ part1,
                      const float* __restrict__ part2,
                      const float* __restrict__ rspart,
                      const float* __restrict__ tspart,
                      float* __restrict__ out, int nch)
{
    __shared__ float red1[16][64], red2[16][64], redt[16][64];
    __shared__ float slw[16], spw[16];

    const int blk = blockIdx.x;          // 0..399
    const int b = blk / NQ, n = blk % NQ;
    const int t = threadIdx.x;
    const int m = t & 63, cg = t >> 6;   // cg in 0..15

    float S1 = 0.f, S2 = 0.f, St = 0.f;
    for (int c = cg; c < nch; c += 16) {
        const long base = ((long)(b * nch + c) * NP + n) * MP + m;
        S1 += part1[base];
        S2 += part2[base];
        St += tspart[(long)(b * nch + c) * MP + m];
    }
    red1[cg][m] = S1; red2[cg][m] = S2; redt[cg][m] = St;

    // Sl/Sp across chunks: threads 0..nch-1 load, per-wave shuffle reduce
    float sl = 0.f, sp = 0.f;
    if (t < nch) {
        const float2 v = *(const float2*)&rspart[((long)(b * nch + t) * NP + n) * 2];
        sl = v.x; sp = v.y;
    }
    #pragma unroll
    for (int off = 32; off; off >>= 1) { sl += __shfl_down(sl, off); sp += __shfl_down(sp, off); }
    if ((t & 63) == 0) { slw[t >> 6] = sl; spw[t >> 6] = sp; }
    __syncthreads();

    if (t < MQ) {
        float Sl = 0.f, Sp = 0.f, s1 = 0.f, s2 = 0.f, st = 0.f;
        #pragma unroll
        for (int w = 0; w < 16; w++) {
            Sl += slw[w]; Sp += spw[w];
            s1 += red1[w][t]; s2 += red2[w][t]; st += redt[w][t];
        }

        // classification: -softmax(logits)[1]
        const float l0 = pred_logits[(b * NQ + n) * 2 + 0];
        const float l1 = pred_logits[(b * NQ + n) * 2 + 1];
        const float p1 = 1.0f / (1.0f + __expf(l0 - l1));

        // style: -softmax(style)[sid]
        const float* stp = &pred_style[(b * NQ + n) * 4];
        const float v0 = stp[0], v1 = stp[1], v2 = stp[2], v3 = stp[3];
        const float mx = fmaxf(fmaxf(v0, v1), fmaxf(v2, v3));
        const float e0 = __expf(v0 - mx), e1 = __expf(v1 - mx),
                    e2 = __expf(v2 - mx), e3 = __expf(v3 - mx);
        const float esum = e0 + e1 + e2 + e3;
        int sid = styles[b * MQ + t];
        sid = min(max(sid, 0), 3);
        const float ps = (sid == 0 ? e0 : sid == 1 ? e1 : sid == 2 ? e2 : e3) / esum;

        const float cost_mask = -(s1 + Sl) * (1.0f / (float)HWSZ);
        const float dice = 1.0f - (2.0f * s2 + 1.0f) / (Sp + st + 1.0f);

        float c = 2.0f * (-p1) + 5.0f * cost_mask + 5.0f * dice + 1.0f * (-ps);
        if (isnan(c)) c = 10000.0f;
        else if (isinf(c)) c = (c > 0.f) ? 10000.0f : -10000.0f;
        out[(b * NQ + n) * MQ + t] = c;
    }
}

extern "C" void kernel_launch(void* const* d_in, const int* in_sizes, int n_in,
                              void* d_out, int out_size, void* d_ws, size_t ws_size,
                              hipStream_t stream) {
    const float* pred_logits = (const float*)d_in[0];
    const float* pred_masks  = (const float*)d_in[1];
    const float* pred_style  = (const float*)d_in[2];
    const float* tgt_masks   = (const float*)d_in[3];
    const int*   styles      = (const int*)d_in[4];
    float* out = (float*)d_out;

    // ws layout: part1/part2 [4][nch][112][64], rspart [4][nch][112][2], tspart [4][nch][64]
    int nch = 8;
    for (int cand = 128; cand >= 8; cand >>= 1) {
        size_t need = (size_t)cand * (2ull * BQ * NP * MP * 4ull
                                      + (size_t)BQ * NP * 2 * 4ull
                                      + (size_t)BQ * MP * 4ull);
        if (need <= ws_size) { nch = cand; break; }
    }
    const int Kc = HWSZ / nch;

    float* part1  = (float*)d_ws;
    float* part2  = part1 + (size_t)BQ * nch * NP * MP;
    float* rspart = part2 + (size_t)BQ * nch * NP * MP;
    float* tspart = rspart + (size_t)BQ * nch * NP * 2;

    // 4 independent waves per 256-thread block; 4*nch*7 wave-jobs total
    matcher_main<<<nch * 7, 256, 0, stream>>>(
        pred_masks, tgt_masks, part1, part2, rspart, tspart, nch, Kc);

    matcher_epilogue<<<BQ * NQ, 1024, 0, stream>>>(
        pred_logits, pred_style, styles, part1, part2, rspart, tspart, out, nch);
}